// Round 16
// baseline (21.019 us; speedup 1.0000x reference)
//
#include <hip/hip_runtime.h>

// FocalLoss (sigmoid focal, mean reduction) — R16.
//   cls_score: [N=4, C=19, H=512, W=512] float32  (76 MiB, streamed once)
//   label:     [N=4, H=512, W=512] int32          (4 MiB, read ONCE)
//
// Ledger (measured):
//  - Single-address atomic tails serialize (11-45ns/op x GRID): two-kernel
//    structure is forced (R2/R7/R9/R14).
//  - Work removal pays ~1:1: trans -3us (R8), LDS -0.8us (R11),
//    label-once -0.5us (R15). Structure levers null so far (R10/R12/R13).
//  - Fixed graph/launch overhead ~6us (R14 datum); partial ~13us vs
//    ~9-12us composite floor.
// R16 lever: occupancy for the label-once body. 2 pixels/thread
// (float2/int2, 8B/lane), 2048 blocks = 8 blocks/CU = 8 waves/SIMD (max),
// doubling the latency-hiding pool vs R15's 4. Body otherwise identical.

#define NC 19
#define IGNORE_INDEX 255
#define ALPHA 0.25f

typedef float f32x2 __attribute__((ext_vector_type(2)));
typedef int   i32x2 __attribute__((ext_vector_type(2)));

constexpr int NBATCH = 4;
constexpr int HW = 512 * 512;                       // 2^18
constexpr int PPP = HW / 2;                         // 131072 pixel-pairs/plane
constexpr int NP = NBATCH * PPP;                    // 524,288 pixel-pairs
constexpr int BLOCK = 256;
constexpr int GRID = NP / BLOCK;                    // 2048, exact (8 blk/CU)
constexpr int BLOCK2 = 1024;
constexpr float INV_TOTAL = 1.0f / (float)(NBATCH * NC * HW);

// Chebyshev-interpolant (7 nodes) of log1p(exp(-u)) on u in [0,6],
// monomials of x = u/3 - 1. Max err ~3.5e-4 (<< 5.5e-3 threshold).
constexpr float A0 =  0.0485865f;
constexpr float A1 = -0.1402039f;
constexpr float A2 =  0.2024491f;
constexpr float A3 = -0.2005852f;
constexpr float A4 =  0.1182934f;
constexpr float A5 = -0.0048016f;
constexpr float A6 = -0.0214538f;

template <int NWAVE>
__device__ __forceinline__ float block_reduce(float v, float* smem) {
    #pragma unroll
    for (int off = 32; off > 0; off >>= 1)
        v += __shfl_down(v, off, 64);
    const int lane = threadIdx.x & 63;
    const int wid  = threadIdx.x >> 6;
    if (lane == 0) smem[wid] = v;
    __syncthreads();
    float s = 0.0f;
    if (threadIdx.x == 0) {
        #pragma unroll
        for (int i = 0; i < NWAVE; ++i) s += smem[i];
    }
    return s;  // valid in thread 0 only
}

__global__ __launch_bounds__(BLOCK) void focal_partial(
        const f32x2* __restrict__ x,
        const i32x2* __restrict__ lab2,
        float*       __restrict__ partial) {
    const int p  = blockIdx.x * BLOCK + threadIdx.x;   // pixel-pair index
    const int n  = p >> 17;                            // p / PPP
    const int pp = p & (PPP - 1);

    // Label + valid mask: loaded/computed ONCE for all 19 channels.
    const i32x2 l2 = lab2[p];
    int   lab[2];
    float av[2];
    #pragma unroll
    for (int j = 0; j < 2; ++j) {
        lab[j] = l2[j];
        av[j]  = ((lab[j] >= 0) && (lab[j] != IGNORE_INDEX)) ? ALPHA : 0.0f;
    }

    const f32x2* base = x + ((size_t)(n * NC) << 17) + pp;

    float acc = 0.0f;
    #pragma unroll
    for (int c = 0; c < NC; ++c) {
        const f32x2 v = base[(size_t)c << 17];
        #pragma unroll
        for (int j = 0; j < 2; ++j) {
            const float xv = v[j];
            const bool  t  = (lab[j] == c);

            // softplus q(|x|) via degree-6 polynomial, no LDS, no trans.
            const float u  = fminf(fabsf(xv), 6.0f);
            const float xx = fmaf(u, 0.33333333f, -1.0f);
            float sp = A6;
            sp = fmaf(sp, xx, A5);
            sp = fmaf(sp, xx, A4);
            sp = fmaf(sp, xx, A3);
            sp = fmaf(sp, xx, A2);
            sp = fmaf(sp, xx, A1);
            sp = fmaf(sp, xx, A0);

            const float y   = t ? -xv : xv;
            const float d   = y + (t ? 1.0f : 0.0f); // t? 1-x : x
            const float w   = av[j] * d * d;
            const float bce = fmaxf(y, 0.0f) + sp;   // = max(x,0)-x*t+q(|x|)
            acc = fmaf(bce, w, acc);
        }
    }

    __shared__ float smem[BLOCK / 64];
    const float s = block_reduce<BLOCK / 64>(acc, smem);
    if (threadIdx.x == 0) partial[blockIdx.x] = s;
}

__global__ __launch_bounds__(BLOCK2) void focal_finalize(
        const float* __restrict__ partial,
        float*       __restrict__ out) {
    float acc = 0.0f;
    for (int i = threadIdx.x; i < GRID; i += BLOCK2)
        acc += partial[i];
    __shared__ float smem[BLOCK2 / 64];
    const float s = block_reduce<BLOCK2 / 64>(acc, smem);
    if (threadIdx.x == 0) out[0] = s * INV_TOTAL;  // LOSS_WEIGHT == 1.0
}

extern "C" void kernel_launch(void* const* d_in, const int* in_sizes, int n_in,
                              void* d_out, int out_size, void* d_ws, size_t ws_size,
                              hipStream_t stream) {
    const f32x2* cls_score = (const f32x2*)d_in[0];
    const i32x2* lab2      = (const i32x2*)d_in[1];
    float* out     = (float*)d_out;
    float* partial = (float*)d_ws;   // GRID floats

    focal_partial<<<GRID, BLOCK, 0, stream>>>(cls_score, lab2, partial);
    focal_finalize<<<1, BLOCK2, 0, stream>>>(partial, out);
}